// Round 1
// baseline (8971.516 us; speedup 1.0000x reference)
//
#include <hip/hip_runtime.h>
#include <hip/hip_bf16.h>
#include <stdint.h>

#define BATCH 32
#define SEQT  512
#define DIM   256
#define UU    512
#define NWG   96   // 32 WGs per layer * 3 layers

typedef __attribute__((ext_vector_type(8))) short bf16x8;
typedef __attribute__((ext_vector_type(4))) float f32x4;

__device__ __forceinline__ short f2bf(float f) {
  uint32_t u = __builtin_bit_cast(uint32_t, f);
  u += 0x7FFFu + ((u >> 16) & 1u);   // RNE
  return (short)(u >> 16);
}

__device__ __forceinline__ float sigm(float x) { return 1.0f / (1.0f + __expf(-x)); }

__device__ __forceinline__ float tanh_fast(float x) {
  float ax = fabsf(x);
  float t = __expf(-2.0f * ax);          // in (0,1], no overflow
  float r = (1.0f - t) / (1.0f + t);
  return copysignf(r, x);
}

// sense-reversing grid barrier, device scope (cross-XCD)
__device__ __forceinline__ void grid_barrier(int* cnt, int* gen) {
  __syncthreads();                        // drains vmcnt -> block's stores in L2
  if (threadIdx.x == 0) {
    __threadfence();                      // writeback L2 (release, agent)
    int g = __hip_atomic_load(gen, __ATOMIC_RELAXED, __HIP_MEMORY_SCOPE_AGENT);
    int a = __hip_atomic_fetch_add(cnt, 1, __ATOMIC_ACQ_REL, __HIP_MEMORY_SCOPE_AGENT);
    if (a == NWG - 1) {
      __hip_atomic_store(cnt, 0, __ATOMIC_RELAXED, __HIP_MEMORY_SCOPE_AGENT);
      __hip_atomic_fetch_add(gen, 1, __ATOMIC_RELEASE, __HIP_MEMORY_SCOPE_AGENT);
    } else {
      while (__hip_atomic_load(gen, __ATOMIC_ACQUIRE, __HIP_MEMORY_SCOPE_AGENT) == g) {
        __builtin_amdgcn_s_sleep(2);
      }
    }
    __threadfence();                      // invalidate stale L1/L2 (acquire)
  }
  __syncthreads();
}

// One layer's persistent scan. 32 WGs per layer; WG jblk owns 16 units (all 4 gates,
// all 32 batch rows). wave = gate. B-fragments live in registers for the whole scan.
template<int LAYER, int XSTEPS, bool XF32>
__device__ void scan_body(
    int jblk,
    const float* __restrict__ xf,       // inputs (layer 0 only), [B][T][D]
    const short* __restrict__ Hprev,    // bf16 [T+1][32][512] (layers 1,2)
    short*       __restrict__ Hcur,     // bf16 [T+1][32][512]
    const float* __restrict__ W,        // [KX][2048]
    const float* __restrict__ R,        // [512][2048]
    const float* __restrict__ bias,     // [2048]
    const float* __restrict__ hinit,    // [512]
    const float* __restrict__ cinit,    // [512]
    int* cnt, int* gen)
{
  const int tid  = threadIdx.x;
  const int g    = tid >> 6;          // wave index = gate (i,f,g,o)
  const int lane = tid & 63;
  const int arow = lane & 15;         // MFMA A row / D col
  const int kq   = lane >> 4;         // k-quarter
  const int jbase = jblk * 16;
  const int colg  = g * UU + jbase + arow;   // column in [4U]

  // ---- one-time: load + convert B fragments into registers ----
  bf16x8 bw[XSTEPS];
  bf16x8 br[16];
#pragma unroll
  for (int ks = 0; ks < XSTEPS; ++ks) {
    bf16x8 v;
#pragma unroll
    for (int jj = 0; jj < 8; ++jj)
      v[jj] = f2bf(W[(size_t)(ks * 32 + kq * 8 + jj) * 2048 + colg]);
    bw[ks] = v;
  }
#pragma unroll
  for (int ks = 0; ks < 16; ++ks) {
    bf16x8 v;
#pragma unroll
    for (int jj = 0; jj < 8; ++jj)
      v[jj] = f2bf(R[(size_t)(ks * 32 + kq * 8 + jj) * 2048 + colg]);
    br[ks] = v;
  }

  // epilogue assignment: thread -> (rows erow, erow+16) x unit eu
  const int eu   = tid & 15;
  const int erow = tid >> 4;
  float biasv[4];
#pragma unroll
  for (int gg = 0; gg < 4; ++gg) biasv[gg] = bias[gg * UU + jbase + eu];
  float c0r = cinit[jbase + eu];
  float c1r = c0r;

  // init tile H[0] = tile(h_init) in bf16
  {
    short hb = f2bf(hinit[jbase + eu]);
    Hcur[(size_t)erow * UU + jbase + eu] = hb;
    Hcur[(size_t)(erow + 16) * UU + jbase + eu] = hb;
  }

  __shared__ float zsm[4][32][16];

  grid_barrier(cnt, gen);

#pragma unroll 1
  for (int s = 0; s < SEQT + 2; ++s) {
    const int t = s - LAYER;
    if (t >= 0 && t < SEQT) {
      f32x4 acc0 = {0.f, 0.f, 0.f, 0.f};
      f32x4 acc1 = {0.f, 0.f, 0.f, 0.f};

      // ---- x @ W part ----
      if constexpr (XF32) {
#pragma unroll
        for (int ks = 0; ks < XSTEPS; ++ks) {
          const int d0 = ks * 32 + kq * 8;
          const float* p0 = xf + ((size_t)arow * SEQT + t) * DIM + d0;
          const float* p1 = xf + ((size_t)(arow + 16) * SEQT + t) * DIM + d0;
          float4 u0 = *(const float4*)p0, u1 = *(const float4*)(p0 + 4);
          float4 v0 = *(const float4*)p1, v1 = *(const float4*)(p1 + 4);
          bf16x8 a0, a1;
          a0[0] = f2bf(u0.x); a0[1] = f2bf(u0.y); a0[2] = f2bf(u0.z); a0[3] = f2bf(u0.w);
          a0[4] = f2bf(u1.x); a0[5] = f2bf(u1.y); a0[6] = f2bf(u1.z); a0[7] = f2bf(u1.w);
          a1[0] = f2bf(v0.x); a1[1] = f2bf(v0.y); a1[2] = f2bf(v0.z); a1[3] = f2bf(v0.w);
          a1[4] = f2bf(v1.x); a1[5] = f2bf(v1.y); a1[6] = f2bf(v1.z); a1[7] = f2bf(v1.w);
          acc0 = __builtin_amdgcn_mfma_f32_16x16x32_bf16(a0, bw[ks], acc0, 0, 0, 0);
          acc1 = __builtin_amdgcn_mfma_f32_16x16x32_bf16(a1, bw[ks], acc1, 0, 0, 0);
        }
      } else {
        const short* xp = Hprev + (size_t)(t + 1) * BATCH * UU;
#pragma unroll
        for (int ks = 0; ks < XSTEPS; ++ks) {
          const int d0 = ks * 32 + kq * 8;
          bf16x8 a0 = *(const bf16x8*)(xp + (size_t)arow * UU + d0);
          bf16x8 a1 = *(const bf16x8*)(xp + (size_t)(arow + 16) * UU + d0);
          acc0 = __builtin_amdgcn_mfma_f32_16x16x32_bf16(a0, bw[ks], acc0, 0, 0, 0);
          acc1 = __builtin_amdgcn_mfma_f32_16x16x32_bf16(a1, bw[ks], acc1, 0, 0, 0);
        }
      }

      // ---- h @ R part ----
      const short* hp = Hcur + (size_t)t * BATCH * UU;
#pragma unroll
      for (int ks = 0; ks < 16; ++ks) {
        const int d0 = ks * 32 + kq * 8;
        bf16x8 a0 = *(const bf16x8*)(hp + (size_t)arow * UU + d0);
        bf16x8 a1 = *(const bf16x8*)(hp + (size_t)(arow + 16) * UU + d0);
        acc0 = __builtin_amdgcn_mfma_f32_16x16x32_bf16(a0, br[ks], acc0, 0, 0, 0);
        acc1 = __builtin_amdgcn_mfma_f32_16x16x32_bf16(a1, br[ks], acc1, 0, 0, 0);
      }

      // ---- exchange z across waves (gates live in different waves) ----
#pragma unroll
      for (int r = 0; r < 4; ++r) {
        zsm[g][kq * 4 + r][arow]      = acc0[r];   // rows 0..15
        zsm[g][16 + kq * 4 + r][arow] = acc1[r];   // rows 16..31
      }
      __syncthreads();

      // ---- gates + state update (fp32), write h as bf16 ----
      short* hout = Hcur + (size_t)(t + 1) * BATCH * UU;
      {
        float zi = zsm[0][erow][eu] + biasv[0];
        float zf = zsm[1][erow][eu] + biasv[1];
        float zg = zsm[2][erow][eu] + biasv[2];
        float zo = zsm[3][erow][eu] + biasv[3];
        float cn = sigm(zf) * c0r + sigm(zi) * tanh_fast(zg);
        c0r = cn;
        hout[(size_t)erow * UU + jbase + eu] = f2bf(sigm(zo) * tanh_fast(cn));
      }
      {
        const int row = erow + 16;
        float zi = zsm[0][row][eu] + biasv[0];
        float zf = zsm[1][row][eu] + biasv[1];
        float zg = zsm[2][row][eu] + biasv[2];
        float zo = zsm[3][row][eu] + biasv[3];
        float cn = sigm(zf) * c1r + sigm(zi) * tanh_fast(zg);
        c1r = cn;
        hout[(size_t)row * UU + jbase + eu] = f2bf(sigm(zo) * tanh_fast(cn));
      }
    }
    grid_barrier(cnt, gen);
  }
}

__global__ __launch_bounds__(256, 1) void lstm_scan(
    const float* __restrict__ inputs,
    const float* __restrict__ W0, const float* __restrict__ R0, const float* __restrict__ b0,
    const float* __restrict__ h0i, const float* __restrict__ c0i,
    const float* __restrict__ W1, const float* __restrict__ R1, const float* __restrict__ b1,
    const float* __restrict__ h1i, const float* __restrict__ c1i,
    const float* __restrict__ W2, const float* __restrict__ R2, const float* __restrict__ b2,
    const float* __restrict__ h2i, const float* __restrict__ c2i,
    short* __restrict__ H0, short* __restrict__ H1, short* __restrict__ H2,
    int* cnt, int* gen)
{
  const int layer = blockIdx.x >> 5;
  const int jblk  = blockIdx.x & 31;
  if (layer == 0)
    scan_body<0, 8, true >(jblk, inputs, nullptr, H0, W0, R0, b0, h0i, c0i, cnt, gen);
  else if (layer == 1)
    scan_body<1, 16, false>(jblk, nullptr, H0, H1, W1, R1, b1, h1i, c1i, cnt, gen);
  else
    scan_body<2, 16, false>(jblk, nullptr, H1, H2, W2, R2, b2, h2i, c2i, cnt, gen);
}

// Y[b][t][:] = H2[t+1][b][:] @ Wd + bd.  Tile: 128 rows x 64 cols per WG.
__global__ __launch_bounds__(256, 2) void dense_out(
    const short* __restrict__ H2,      // [T+1][32][512]
    const float* __restrict__ Wd,      // [512][256]
    const float* __restrict__ bd,      // [256]
    float* __restrict__ out)           // [32][512][256]
{
  const int mblock = blockIdx.x;       // 0..127
  const int nblock = blockIdx.y;       // 0..3
  const int tid  = threadIdx.x;
  const int wave = tid >> 6;
  const int lane = tid & 63;
  const int col  = lane & 15;
  const int kq   = lane >> 4;

  __shared__ short wlds[64][264];      // transposed Wd slice (half-K), padded

  f32x4 acc[2][4];
#pragma unroll
  for (int mi = 0; mi < 2; ++mi)
#pragma unroll
    for (int ni = 0; ni < 4; ++ni)
      acc[mi][ni] = f32x4{0.f, 0.f, 0.f, 0.f};

  const short* Abase = H2 + (size_t)32 * UU;   // skip the init tile

  for (int half = 0; half < 2; ++half) {
    __syncthreads();
    for (int idx = tid; idx < 256 * 64; idx += 256) {
      int k = idx >> 6;
      int c = idx & 63;
      wlds[c][k] = f2bf(Wd[(size_t)(half * 256 + k) * 256 + nblock * 64 + c]);
    }
    __syncthreads();
#pragma unroll
    for (int ks = 0; ks < 8; ++ks) {
      const int d0g = half * 256 + ks * 32 + kq * 8;   // global k
      const int d0l = ks * 32 + kq * 8;                // LDS-local k
      const size_t r0 = (size_t)(mblock * 128 + wave * 32 + col) * UU;
      const size_t r1 = (size_t)(mblock * 128 + wave * 32 + 16 + col) * UU;
      bf16x8 a0 = *(const bf16x8*)(Abase + r0 + d0g);
      bf16x8 a1 = *(const bf16x8*)(Abase + r1 + d0g);
#pragma unroll
      for (int ni = 0; ni < 4; ++ni) {
        bf16x8 bv = *(const bf16x8*)(&wlds[ni * 16 + col][d0l]);
        acc[0][ni] = __builtin_amdgcn_mfma_f32_16x16x32_bf16(a0, bv, acc[0][ni], 0, 0, 0);
        acc[1][ni] = __builtin_amdgcn_mfma_f32_16x16x32_bf16(a1, bv, acc[1][ni], 0, 0, 0);
      }
    }
  }

#pragma unroll
  for (int ni = 0; ni < 4; ++ni) {
    float bdv = bd[nblock * 64 + ni * 16 + col];
#pragma unroll
    for (int mi = 0; mi < 2; ++mi) {
#pragma unroll
      for (int r = 0; r < 4; ++r) {
        int grow = mblock * 128 + wave * 32 + mi * 16 + kq * 4 + r;
        int t = grow >> 5, b = grow & 31;
        out[((size_t)b * SEQT + t) * DIM + nblock * 64 + ni * 16 + col] = acc[mi][ni][r] + bdv;
      }
    }
  }
}

extern "C" void kernel_launch(void* const* d_in, const int* in_sizes, int n_in,
                              void* d_out, int out_size, void* d_ws, size_t ws_size,
                              hipStream_t stream) {
  const float* inputs = (const float*)d_in[0];
  const float* W0 = (const float*)d_in[1];
  const float* R0 = (const float*)d_in[2];
  const float* b0 = (const float*)d_in[3];
  const float* h0 = (const float*)d_in[4];
  const float* c0 = (const float*)d_in[5];
  const float* W1 = (const float*)d_in[6];
  const float* R1 = (const float*)d_in[7];
  const float* b1 = (const float*)d_in[8];
  const float* h1 = (const float*)d_in[9];
  const float* c1 = (const float*)d_in[10];
  const float* W2 = (const float*)d_in[11];
  const float* R2 = (const float*)d_in[12];
  const float* b2 = (const float*)d_in[13];
  const float* h2 = (const float*)d_in[14];
  const float* c2 = (const float*)d_in[15];
  const float* Wd = (const float*)d_in[16];
  const float* bd = (const float*)d_in[17];

  int* cnt = (int*)d_ws;
  int* gen = cnt + 1;
  char* base = (char*)d_ws + 256;
  size_t Hbytes = (size_t)(SEQT + 1) * BATCH * UU * sizeof(short);  // ~16.0 MB
  short* H0 = (short*)(base);
  short* H1 = (short*)(base + Hbytes);
  short* H2 = (short*)(base + 2 * Hbytes);

  hipMemsetAsync(d_ws, 0, 16, stream);   // barrier counter + generation

  hipLaunchKernelGGL(lstm_scan, dim3(NWG), dim3(256), 0, stream,
                     inputs, W0, R0, b0, h0, c0, W1, R1, b1, h1, c1,
                     W2, R2, b2, h2, c2, H0, H1, H2, cnt, gen);

  hipLaunchKernelGGL(dense_out, dim3(128, 4), dim3(256), 0, stream,
                     H2, Wd, bd, (float*)d_out);
}

// Round 2
// 3576.073 us; speedup vs baseline: 2.5088x; 2.5088x over previous
//
#include <hip/hip_runtime.h>
#include <hip/hip_bf16.h>
#include <stdint.h>

#define BATCH 32
#define SEQT  512
#define DIM   256
#define UU    512
#define WGL   64          // workgroups per layer
#define ROWS  16          // batch rows per workgroup

typedef __attribute__((ext_vector_type(8))) short bf16x8;
typedef __attribute__((ext_vector_type(4))) float f32x4;

__device__ __forceinline__ short f2bf(float f) {
  uint32_t u = __builtin_bit_cast(uint32_t, f);
  u += 0x7FFFu + ((u >> 16) & 1u);   // RNE
  return (short)(u >> 16);
}

__device__ __forceinline__ float sigm(float x) { return 1.0f / (1.0f + __expf(-x)); }

__device__ __forceinline__ float tanh_fast(float x) {
  float ax = fabsf(x);
  float t = __expf(-2.0f * ax);
  float r = (1.0f - t) / (1.0f + t);
  return copysignf(r, x);
}

// store that is visible at the device coherence point (L3/MALL) once vmcnt drains
__device__ __forceinline__ void store_short_sc01(short* p, short v) {
  uint32_t d = (uint16_t)v;
  asm volatile("global_store_short %0, %1, off sc0 sc1" :: "v"(p), "v"(d) : "memory");
}

template<int XSTEPS, bool XF32>
__device__ void scan_body(
    int jblk, int rblk,
    const float* __restrict__ xf,       // [B][T][D] (layer 0 only)
    const short* __restrict__ Hprev,    // bf16 [T+1][32][512]
    short*       __restrict__ Hcur,     // bf16 [T+1][32][512]
    const float* __restrict__ W,        // [KX][2048]
    const float* __restrict__ R,        // [512][2048]
    const float* __restrict__ bias,     // [2048]
    const float* __restrict__ hinit,    // [512]
    const float* __restrict__ cinit,    // [512]
    int* cntPrev, int* cntOwn)
{
  const int tid  = threadIdx.x;
  const int g    = tid >> 6;            // wave = gate (i,f,g,o)
  const int lane = tid & 63;
  const int arow = lane & 15;           // MFMA A row (batch) / B col (unit)
  const int kq   = lane >> 4;
  const int jbase = jblk * 16;
  const int rbase = rblk * ROWS;
  const int colg  = g * UU + jbase + arow;

  // one-time: weight B-fragments into registers for the whole scan
  bf16x8 bw[XSTEPS];
  bf16x8 br[16];
#pragma unroll
  for (int ks = 0; ks < XSTEPS; ++ks) {
    bf16x8 v;
#pragma unroll
    for (int jj = 0; jj < 8; ++jj)
      v[jj] = f2bf(W[(size_t)(ks * 32 + kq * 8 + jj) * 2048 + colg]);
    bw[ks] = v;
  }
#pragma unroll
  for (int ks = 0; ks < 16; ++ks) {
    bf16x8 v;
#pragma unroll
    for (int jj = 0; jj < 8; ++jj)
      v[jj] = f2bf(R[(size_t)(ks * 32 + kq * 8 + jj) * 2048 + colg]);
    br[ks] = v;
  }

  // epilogue mapping: one (row, unit) per thread
  const int eu   = tid & 15;
  const int erow = tid >> 4;            // 0..15
  float biasv[4];
#pragma unroll
  for (int gg = 0; gg < 4; ++gg) biasv[gg] = bias[gg * UU + jbase + eu];
  float cr = cinit[jbase + eu];

  // init tile H[0]
  store_short_sc01(&Hcur[(size_t)(rbase + erow) * UU + jbase + eu], f2bf(hinit[jbase + eu]));
  asm volatile("s_waitcnt vmcnt(0)" ::: "memory");
  __syncthreads();
  if (tid == 0)
    __hip_atomic_fetch_add(cntOwn, 1, __ATOMIC_RELAXED, __HIP_MEMORY_SCOPE_AGENT);

  __shared__ float zsm[4][ROWS][16];

#pragma unroll 1
  for (int t = 0; t < SEQT; ++t) {
    if (tid == 0) {
      const int needOwn = WGL * (t + 1);   // own layer finished step t-1
      while (__hip_atomic_load(cntOwn, __ATOMIC_RELAXED, __HIP_MEMORY_SCOPE_AGENT) < needOwn) {}
      if constexpr (!XF32) {
        const int needPrev = WGL * (t + 2); // prev layer finished step t
        while (__hip_atomic_load(cntPrev, __ATOMIC_RELAXED, __HIP_MEMORY_SCOPE_AGENT) < needPrev) {}
      }
    }
    __syncthreads();

    f32x4 acc = {0.f, 0.f, 0.f, 0.f};

    // x @ W
    if constexpr (XF32) {
      const float* p = xf + ((size_t)(rbase + arow) * SEQT + t) * DIM + kq * 8;
#pragma unroll
      for (int ks = 0; ks < XSTEPS; ++ks) {
        float4 u0 = *(const float4*)(p + ks * 32);
        float4 u1 = *(const float4*)(p + ks * 32 + 4);
        bf16x8 a;
        a[0] = f2bf(u0.x); a[1] = f2bf(u0.y); a[2] = f2bf(u0.z); a[3] = f2bf(u0.w);
        a[4] = f2bf(u1.x); a[5] = f2bf(u1.y); a[6] = f2bf(u1.z); a[7] = f2bf(u1.w);
        acc = __builtin_amdgcn_mfma_f32_16x16x32_bf16(a, bw[ks], acc, 0, 0, 0);
      }
    } else {
      const short* xp = Hprev + ((size_t)(t + 1) * BATCH + rbase + arow) * UU + kq * 8;
#pragma unroll
      for (int ks = 0; ks < XSTEPS; ++ks) {
        bf16x8 a = *(const bf16x8*)(xp + ks * 32);
        acc = __builtin_amdgcn_mfma_f32_16x16x32_bf16(a, bw[ks], acc, 0, 0, 0);
      }
    }

    // h @ R
    const short* hp = Hcur + ((size_t)t * BATCH + rbase + arow) * UU + kq * 8;
#pragma unroll
    for (int ks = 0; ks < 16; ++ks) {
      bf16x8 a = *(const bf16x8*)(hp + ks * 32);
      acc = __builtin_amdgcn_mfma_f32_16x16x32_bf16(a, br[ks], acc, 0, 0, 0);
    }

    // exchange z across waves (gates live in different waves)
#pragma unroll
    for (int r = 0; r < 4; ++r)
      zsm[g][kq * 4 + r][arow] = acc[r];
    __syncthreads();

    // gates + state update (fp32), write h as bf16 (visible at L3)
    {
      float zi = zsm[0][erow][eu] + biasv[0];
      float zf = zsm[1][erow][eu] + biasv[1];
      float zg = zsm[2][erow][eu] + biasv[2];
      float zo = zsm[3][erow][eu] + biasv[3];
      cr = sigm(zf) * cr + sigm(zi) * tanh_fast(zg);
      float hv = sigm(zo) * tanh_fast(cr);
      store_short_sc01(&Hcur[((size_t)(t + 1) * BATCH + rbase + erow) * UU + jbase + eu], f2bf(hv));
    }
    asm volatile("s_waitcnt vmcnt(0)" ::: "memory");  // own stores acked at L3
    __syncthreads();                                  // everyone's stores acked
    if (tid == 0)
      __hip_atomic_fetch_add(cntOwn, 1, __ATOMIC_RELAXED, __HIP_MEMORY_SCOPE_AGENT);
  }
}

__global__ __launch_bounds__(256, 1) void lstm_scan(
    const float* __restrict__ inputs,
    const float* __restrict__ W0, const float* __restrict__ R0, const float* __restrict__ b0,
    const float* __restrict__ h0i, const float* __restrict__ c0i,
    const float* __restrict__ W1, const float* __restrict__ R1, const float* __restrict__ b1,
    const float* __restrict__ h1i, const float* __restrict__ c1i,
    const float* __restrict__ W2, const float* __restrict__ R2, const float* __restrict__ b2,
    const float* __restrict__ h2i, const float* __restrict__ c2i,
    short* __restrict__ H0, short* __restrict__ H1, short* __restrict__ H2,
    int* flags)
{
  const int layer = blockIdx.x / WGL;
  const int sub   = blockIdx.x % WGL;
  const int jblk  = sub & 31;
  const int rblk  = sub >> 5;
  int* c0 = flags;
  int* c1 = flags + 32;   // 128B apart
  int* c2 = flags + 64;
  if (layer == 0)
    scan_body<8,  true >(jblk, rblk, inputs, nullptr, H0, W0, R0, b0, h0i, c0i, nullptr, c0);
  else if (layer == 1)
    scan_body<16, false>(jblk, rblk, nullptr, H0, H1, W1, R1, b1, h1i, c1i, c0, c1);
  else
    scan_body<16, false>(jblk, rblk, nullptr, H1, H2, W2, R2, b2, h2i, c2i, c1, c2);
}

// Y[b][t][:] = H2[t+1][b][:] @ Wd + bd.  Tile: 128 rows x 64 cols per WG.
__global__ __launch_bounds__(256, 2) void dense_out(
    const short* __restrict__ H2,      // [T+1][32][512]
    const float* __restrict__ Wd,      // [512][256]
    const float* __restrict__ bd,      // [256]
    float* __restrict__ out)           // [32][512][256]
{
  const int mblock = blockIdx.x;       // 0..127
  const int nblock = blockIdx.y;       // 0..3
  const int tid  = threadIdx.x;
  const int wave = tid >> 6;
  const int lane = tid & 63;
  const int col  = lane & 15;
  const int kq   = lane >> 4;

  __shared__ short wlds[64][264];      // transposed Wd slice (half-K), padded

  f32x4 acc[2][4];
#pragma unroll
  for (int mi = 0; mi < 2; ++mi)
#pragma unroll
    for (int ni = 0; ni < 4; ++ni)
      acc[mi][ni] = f32x4{0.f, 0.f, 0.f, 0.f};

  const short* Abase = H2 + (size_t)32 * UU;   // skip the init tile

  for (int half = 0; half < 2; ++half) {
    __syncthreads();
    for (int idx = tid; idx < 256 * 64; idx += 256) {
      int k = idx >> 6;
      int c = idx & 63;
      wlds[c][k] = f2bf(Wd[(size_t)(half * 256 + k) * 256 + nblock * 64 + c]);
    }
    __syncthreads();
#pragma unroll
    for (int ks = 0; ks < 8; ++ks) {
      const int d0g = half * 256 + ks * 32 + kq * 8;
      const int d0l = ks * 32 + kq * 8;
      const size_t r0 = (size_t)(mblock * 128 + wave * 32 + col) * UU;
      const size_t r1 = (size_t)(mblock * 128 + wave * 32 + 16 + col) * UU;
      bf16x8 a0 = *(const bf16x8*)(Abase + r0 + d0g);
      bf16x8 a1 = *(const bf16x8*)(Abase + r1 + d0g);
#pragma unroll
      for (int ni = 0; ni < 4; ++ni) {
        bf16x8 bv = *(const bf16x8*)(&wlds[ni * 16 + col][d0l]);
        acc[0][ni] = __builtin_amdgcn_mfma_f32_16x16x32_bf16(a0, bv, acc[0][ni], 0, 0, 0);
        acc[1][ni] = __builtin_amdgcn_mfma_f32_16x16x32_bf16(a1, bv, acc[1][ni], 0, 0, 0);
      }
    }
  }

#pragma unroll
  for (int ni = 0; ni < 4; ++ni) {
    float bdv = bd[nblock * 64 + ni * 16 + col];
#pragma unroll
    for (int mi = 0; mi < 2; ++mi) {
#pragma unroll
      for (int r = 0; r < 4; ++r) {
        int grow = mblock * 128 + wave * 32 + mi * 16 + kq * 4 + r;
        int t = grow >> 5, b = grow & 31;
        out[((size_t)b * SEQT + t) * DIM + nblock * 64 + ni * 16 + col] = acc[mi][ni][r] + bdv;
      }
    }
  }
}

extern "C" void kernel_launch(void* const* d_in, const int* in_sizes, int n_in,
                              void* d_out, int out_size, void* d_ws, size_t ws_size,
                              hipStream_t stream) {
  const float* inputs = (const float*)d_in[0];
  const float* W0 = (const float*)d_in[1];
  const float* R0 = (const float*)d_in[2];
  const float* b0 = (const float*)d_in[3];
  const float* h0 = (const float*)d_in[4];
  const float* c0 = (const float*)d_in[5];
  const float* W1 = (const float*)d_in[6];
  const float* R1 = (const float*)d_in[7];
  const float* b1 = (const float*)d_in[8];
  const float* h1 = (const float*)d_in[9];
  const float* c1 = (const float*)d_in[10];
  const float* W2 = (const float*)d_in[11];
  const float* R2 = (const float*)d_in[12];
  const float* b2 = (const float*)d_in[13];
  const float* h2 = (const float*)d_in[14];
  const float* c2 = (const float*)d_in[15];
  const float* Wd = (const float*)d_in[16];
  const float* bd = (const float*)d_in[17];

  int* flags = (int*)d_ws;
  char* base = (char*)d_ws + 4096;
  size_t Hbytes = (size_t)(SEQT + 1) * BATCH * UU * sizeof(short);  // ~16.8 MB
  short* H0 = (short*)(base);
  short* H1 = (short*)(base + Hbytes);
  short* H2 = (short*)(base + 2 * Hbytes);

  hipMemsetAsync(d_ws, 0, 4096, stream);   // arrival counters

  hipLaunchKernelGGL(lstm_scan, dim3(3 * WGL), dim3(256), 0, stream,
                     inputs, W0, R0, b0, h0, c0, W1, R1, b1, h1, c1,
                     W2, R2, b2, h2, c2, H0, H1, H2, flags);

  hipLaunchKernelGGL(dense_out, dim3(128, 4), dim3(256), 0, stream,
                     H2, Wd, bd, (float*)d_out);
}